// Round 17
// baseline (210.596 us; speedup 1.0000x reference)
//
#include <hip/hip_runtime.h>
#include <hip/hip_fp16.h>
#include <type_traits>

#define F_IN 128
#define NPART 8

typedef _Float16 f16x8 __attribute__((ext_vector_type(8)));
typedef _Float16 f16x4 __attribute__((ext_vector_type(4)));
typedef float f32x4 __attribute__((ext_vector_type(4)));

// ---------------- setup: weight transpose->fp16 + deg zero (fused) ----------------

__global__ void setup_kernel(const float* __restrict__ W0, const float* __restrict__ W1,
                             const float* __restrict__ W2, __half* __restrict__ Wt0,
                             __half* __restrict__ Wt1, __half* __restrict__ Wt2,
                             int* __restrict__ deg, int N) {
    int idx = blockIdx.x * 256 + threadIdx.x;
    if (idx < 16384) {                          // W0: [128][128]
        int k = idx >> 7, n = idx & 127;
        Wt0[n * 128 + k] = __float2half_rn(W0[idx]);
    } else if (idx < 32768) {                   // W1: [128][128]
        int j = idx - 16384;
        int k = j >> 7, n = j & 127;
        Wt1[n * 128 + k] = __float2half_rn(W1[j]);
    } else if (idx < 40960) {                   // W2: [128][64]
        int j = idx - 32768;
        int k = j >> 6, n = j & 63;
        Wt2[n * 128 + k] = __float2half_rn(W2[j]);
    }
    if (idx < N) deg[idx] = 0;                  // grid covers max(40960, N)
}

// ---------------- degree: single-pass (R10 proved partitioning neutral) ----------------

__global__ void deg_kernel(const int* __restrict__ dst, int* __restrict__ deg, int E) {
    int i = blockIdx.x * blockDim.x + threadIdx.x;
    if (i < E) atomicAdd(&deg[dst[i]], 1);
}

// ---------------- CSR build ----------------

__global__ void scan_blocks(const int* __restrict__ deg, int* __restrict__ rp,
                            int* __restrict__ bsum, int N) {
    __shared__ int tmp[256];
    int t = threadIdx.x, i = blockIdx.x * 256 + t;
    int v = (i < N) ? deg[i] : 0;
    tmp[t] = v;
    __syncthreads();
    for (int off = 1; off < 256; off <<= 1) {
        int a = (t >= off) ? tmp[t - off] : 0;
        __syncthreads();
        tmp[t] += a;
        __syncthreads();
    }
    if (i < N) rp[i] = tmp[t] - v;
    if (t == 255) bsum[blockIdx.x] = tmp[255];
}

// folds bsum prefix (tree-reduce of bsum[0..blockIdx)) + dinv compute
__global__ void add_offsets_kernel(int* __restrict__ rp, const int* __restrict__ bsum,
                                   int* __restrict__ cursor, const int* __restrict__ deg,
                                   float* __restrict__ dinv, int N, int nb) {
    __shared__ int tmp[256];
    int t = threadIdx.x;
    tmp[t] = (t < nb && t < (int)blockIdx.x) ? bsum[t] : 0;
    __syncthreads();
    for (int s = 128; s > 0; s >>= 1) {
        if (t < s) tmp[t] += tmp[t + s];
        __syncthreads();
    }
    int base = tmp[0];
    int i = blockIdx.x * 256 + t;
    if (i < N) {
        int r = rp[i] + base;
        rp[i] = r;
        cursor[i] = r;
        dinv[i] = rsqrtf((float)(deg[i] + 1));   // +1 self-loop; always > 0
    }
}

// dst-partitioned CSR build (u16 payload; partitions keep cursor+csr slices
// XCD-L2-private so the u16 scatter coalesces before writeback).
__global__ __launch_bounds__(256) void build_csr_kernel(
    const int* __restrict__ src, const int* __restrict__ dst,
    int* __restrict__ cursor, unsigned short* __restrict__ csr_src,
    int E, int psize)
{
    const int part  = blockIdx.x % NPART;
    const int bslot = blockIdx.x / NPART;
    const int nb    = gridDim.x / NPART;
    const int lo = part * psize;
    const int hi = lo + psize;
    for (int e = bslot * 256 + threadIdx.x; e < E; e += nb * 256) {
        int d = dst[e];
        if (d >= lo && d < hi) {
            int pos = atomicAdd(&cursor[d], 1);
            csr_src[pos] = (unsigned short)src[e];
        }
    }
}

// ---------------- MFMA GEMM: g = fp16(dinv * (X @ W)) ----------------
// BM=64 (4 waves x 16 rows), BN=128 or 64. A from global (row-major X),
// B = Wt[n][k] fp16 staged in LDS with +8-half row pad.
// Fragment maps: A: m=lane&15, k=ks*32+(lane>>4)*8+j ; B: n=lane&15, same k.
// C/D: col=lane&15, row=(lane>>4)*4+reg  [HW-verified m89/m91].

template<int BN, typename XT>
__global__ __launch_bounds__(256) void gemm_mfma_kernel(
    const XT* __restrict__ X, const __half* __restrict__ Wt,
    const float* __restrict__ dinv, __half* __restrict__ g, int N)
{
    constexpr int K  = 128;
    constexpr int KP = K + 8;
    constexpr int NT = BN / 16;
    __shared__ __half Ws[BN * KP];

    const int tid = threadIdx.x;
    for (int c = tid; c < BN * (K / 8); c += 256) {
        int n  = c >> 4;
        int k8 = c & 15;
        *(f16x8*)&Ws[n * KP + k8 * 8] =
            *(const f16x8*)((const _Float16*)Wt + n * K + k8 * 8);
    }
    __syncthreads();

    const int lane = tid & 63;
    const int w    = tid >> 6;
    const int lrow = lane & 15;
    const int kg   = lane >> 4;
    const int row0 = blockIdx.x * 64 + w * 16;
    const int gr   = row0 + lrow;

    f32x4 acc[NT];
    #pragma unroll
    for (int t = 0; t < NT; ++t) acc[t] = (f32x4){0.f, 0.f, 0.f, 0.f};

    #pragma unroll
    for (int ks = 0; ks < 4; ++ks) {
        const int k0 = ks * 32 + kg * 8;
        f16x8 a = {};
        if constexpr (sizeof(XT) == 4) {
            if (gr < N) {
                const float* p = (const float*)X + (size_t)gr * K + k0;
                float4 x0 = *(const float4*)p;
                float4 x1 = *(const float4*)(p + 4);
                a[0] = (_Float16)x0.x; a[1] = (_Float16)x0.y;
                a[2] = (_Float16)x0.z; a[3] = (_Float16)x0.w;
                a[4] = (_Float16)x1.x; a[5] = (_Float16)x1.y;
                a[6] = (_Float16)x1.z; a[7] = (_Float16)x1.w;
            }
        } else {
            if (gr < N)
                a = *(const f16x8*)((const _Float16*)X + (size_t)gr * K + k0);
        }
        #pragma unroll
        for (int t = 0; t < NT; ++t) {
            f16x8 b = *(const f16x8*)&Ws[(t * 16 + lrow) * KP + k0];
            acc[t] = __builtin_amdgcn_mfma_f32_16x16x32_f16(a, b, acc[t], 0, 0, 0);
        }
    }

    #pragma unroll
    for (int r = 0; r < 4; ++r) {
        int m = row0 + kg * 4 + r;
        if (m < N) {
            float dn = dinv[m];
            #pragma unroll
            for (int t = 0; t < NT; ++t)
                g[(size_t)m * BN + t * 16 + lrow] = __float2half_rn(dn * acc[t][r]);
        }
    }
}

// ---------------- CSR aggregation + finalize ----------------
// 16 lanes per dst node (4 nodes/wave), 16B f16x8 gathers. NT hints: csr
// (read-once) loaded non-temporal, outputs (write-once) stored non-temporal,
// so L2 residency is reserved for the reused g rows.

template<int FO, bool RELU, typename OT>
__global__ __launch_bounds__(256) void aggregate_kernel(
    const __half* __restrict__ g, const int* __restrict__ rp, const int* __restrict__ deg,
    const unsigned short* __restrict__ csr, const float* __restrict__ dinv,
    const float* __restrict__ bias, OT* __restrict__ out, int N)
{
    constexpr int PER = FO / 16;   // 8 (FO=128) or 4 (FO=64)
    using VT = typename std::conditional<PER == 8, f16x8, f16x4>::type;

    int gid  = blockIdx.x * 256 + threadIdx.x;
    int node = gid >> 4;
    int lane = gid & 15;
    if (node >= N) return;

    int start = rp[node];
    int dg    = deg[node];

    const _Float16* gb = (const _Float16*)g + (size_t)lane * PER;

    float a[PER];
    {   // self-loop term
        VT v = *(const VT*)(gb + (size_t)node * FO);
        #pragma unroll
        for (int p = 0; p < PER; ++p) a[p] = (float)v[p];
    }

    int j = 0;
    for (; j + 7 < dg; j += 8) {
        int s[8];
        #pragma unroll
        for (int q = 0; q < 8; ++q)
            s[q] = __builtin_nontemporal_load(&csr[start + j + q]);
        VT v[8];
        #pragma unroll
        for (int q = 0; q < 8; ++q) v[q] = *(const VT*)(gb + (size_t)s[q] * FO);
        #pragma unroll
        for (int p = 0; p < PER; ++p)
            a[p] += (((float)v[0][p] + (float)v[1][p]) + ((float)v[2][p] + (float)v[3][p]))
                  + (((float)v[4][p] + (float)v[5][p]) + ((float)v[6][p] + (float)v[7][p]));
    }
    for (; j + 3 < dg; j += 4) {
        int s0 = __builtin_nontemporal_load(&csr[start + j]);
        int s1 = __builtin_nontemporal_load(&csr[start + j + 1]);
        int s2 = __builtin_nontemporal_load(&csr[start + j + 2]);
        int s3 = __builtin_nontemporal_load(&csr[start + j + 3]);
        VT v0 = *(const VT*)(gb + (size_t)s0 * FO);
        VT v1 = *(const VT*)(gb + (size_t)s1 * FO);
        VT v2 = *(const VT*)(gb + (size_t)s2 * FO);
        VT v3 = *(const VT*)(gb + (size_t)s3 * FO);
        #pragma unroll
        for (int p = 0; p < PER; ++p)
            a[p] += ((float)v0[p] + (float)v1[p]) + ((float)v2[p] + (float)v3[p]);
    }
    for (; j < dg; ++j) {
        int s0 = __builtin_nontemporal_load(&csr[start + j]);
        VT v0 = *(const VT*)(gb + (size_t)s0 * FO);
        #pragma unroll
        for (int p = 0; p < PER; ++p) a[p] += (float)v0[p];
    }

    float dn = dinv[node];
    float o[PER];
    #pragma unroll
    for (int p = 0; p < PER; ++p) {
        o[p] = fmaf(dn, a[p], bias[lane * PER + p]);
        if (RELU) o[p] = fmaxf(o[p], 0.f);
    }

    if constexpr (sizeof(OT) == 2) {
        VT h;
        #pragma unroll
        for (int p = 0; p < PER; ++p) h[p] = (_Float16)o[p];
        __builtin_nontemporal_store(h, (VT*)((_Float16*)out + (size_t)node * FO + lane * PER));
    } else {
        float* op = (float*)out + (size_t)node * FO + lane * PER;
        #pragma unroll
        for (int q = 0; q < PER / 4; ++q) {
            f32x4 f4 = {o[4 * q], o[4 * q + 1], o[4 * q + 2], o[4 * q + 3]};
            __builtin_nontemporal_store(f4, (f32x4*)(op + 4 * q));
        }
    }
}

// ---------------- launch ----------------

extern "C" void kernel_launch(void* const* d_in, const int* in_sizes, int n_in,
                              void* d_out, int out_size, void* d_ws, size_t ws_size,
                              hipStream_t stream) {
    const float* x  = (const float*)d_in[0];
    const int*   ei = (const int*)d_in[1];    // harness passes integer inputs as int32
    const float* W0 = (const float*)d_in[2];
    const float* b0 = (const float*)d_in[3];
    const float* W1 = (const float*)d_in[4];
    const float* b1 = (const float*)d_in[5];
    const float* W2 = (const float*)d_in[6];
    const float* b2 = (const float*)d_in[7];
    float* out = (float*)d_out;

    const int N = in_sizes[0] / F_IN;
    const int E = in_sizes[1] / 2;
    const int* src = ei;
    const int* dst = ei + E;

    char* ws = (char*)d_ws;
    size_t off = 0;
    __half* bufA  = (__half*)(ws + off); off += (size_t)N * 128 * 2;  // g (fp16)
    __half* bufB  = (__half*)(ws + off); off += (size_t)N * 128 * 2;  // features (fp16)
    float* dinv   = (float*)(ws + off); off += (size_t)N * 4;
    int*   deg    = (int*)  (ws + off); off += (size_t)N * 4;
    int*   rowptr = (int*)  (ws + off); off += (size_t)N * 4;
    int*   cursor = (int*)  (ws + off); off += (size_t)N * 4;
    int*   bsum   = (int*)  (ws + off); off += 256 * 4;
    unsigned short* csr = (unsigned short*)(ws + off); off += (size_t)E * 2;
    off = (off + 255) & ~(size_t)255;
    __half* wt0 = (__half*)(ws + off); off += 128 * 128 * 2;
    __half* wt1 = (__half*)(ws + off); off += 128 * 128 * 2;
    __half* wt2 = (__half*)(ws + off); off += 64 * 128 * 2;

    const int nb_nodes = (N + 255) / 256;   // 196 blocks -> fits 256-wide bsum reduce
    const int nb_setup = (((N > 40960 ? N : 40960) + 255) / 256);
    const int nb_edges = (E + 255) / 256;
    const int nb_aggr  = (N * 16 + 255) / 256;
    const int nb_gemm  = (N + 63) / 64;
    const int psize    = (N + NPART - 1) / NPART;

    setup_kernel<<<nb_setup, 256, 0, stream>>>(W0, W1, W2, wt0, wt1, wt2, deg, N);
    deg_kernel<<<nb_edges, 256, 0, stream>>>(dst, deg, E);
    scan_blocks<<<nb_nodes, 256, 0, stream>>>(deg, rowptr, bsum, N);
    add_offsets_kernel<<<nb_nodes, 256, 0, stream>>>(rowptr, bsum, cursor, deg, dinv, N, nb_nodes);
    build_csr_kernel<<<NPART * 128, 256, 0, stream>>>(src, dst, cursor, csr, E, psize);

    // ---- layer 0: x (fp32) -> bufA (g fp16) -> bufB (fp16) ----
    gemm_mfma_kernel<128, float><<<nb_gemm, 256, 0, stream>>>(x, wt0, dinv, bufA, N);
    aggregate_kernel<128, true, __half><<<nb_aggr, 256, 0, stream>>>(bufA, rowptr, deg, csr, dinv, b0, bufB, N);

    // ---- layer 1: bufB (fp16) -> bufA (g fp16) -> bufB (fp16) ----
    gemm_mfma_kernel<128, __half><<<nb_gemm, 256, 0, stream>>>(bufB, wt1, dinv, bufA, N);
    aggregate_kernel<128, true, __half><<<nb_aggr, 256, 0, stream>>>(bufA, rowptr, deg, csr, dinv, b1, bufB, N);

    // ---- layer 2: bufB (fp16) -> bufA (g fp16, N*64) -> out (fp32) ----
    gemm_mfma_kernel<64, __half><<<nb_gemm, 256, 0, stream>>>(bufB, wt2, dinv, bufA, N);
    aggregate_kernel<64, false, float><<<nb_aggr, 256, 0, stream>>>(bufA, rowptr, deg, csr, dinv, b2, out, N);
}

// Round 18
// 201.619 us; speedup vs baseline: 1.0445x; 1.0445x over previous
//
#include <hip/hip_runtime.h>
#include <hip/hip_fp16.h>
#include <type_traits>

#define F_IN 128
#define NPART 8

typedef _Float16 f16x8 __attribute__((ext_vector_type(8)));
typedef _Float16 f16x4 __attribute__((ext_vector_type(4)));
typedef float f32x4 __attribute__((ext_vector_type(4)));

// ---------------- setup: weight transpose->fp16 + deg zero (fused) ----------------

__global__ void setup_kernel(const float* __restrict__ W0, const float* __restrict__ W1,
                             const float* __restrict__ W2, __half* __restrict__ Wt0,
                             __half* __restrict__ Wt1, __half* __restrict__ Wt2,
                             int* __restrict__ deg, int N) {
    int idx = blockIdx.x * 256 + threadIdx.x;
    if (idx < 16384) {                          // W0: [128][128]
        int k = idx >> 7, n = idx & 127;
        Wt0[n * 128 + k] = __float2half_rn(W0[idx]);
    } else if (idx < 32768) {                   // W1: [128][128]
        int j = idx - 16384;
        int k = j >> 7, n = j & 127;
        Wt1[n * 128 + k] = __float2half_rn(W1[j]);
    } else if (idx < 40960) {                   // W2: [128][64]
        int j = idx - 32768;
        int k = j >> 6, n = j & 63;
        Wt2[n * 128 + k] = __float2half_rn(W2[j]);
    }
    if (idx < N) deg[idx] = 0;                  // grid covers max(40960, N)
}

// ---------------- degree (dst-partitioned; R17 showed single-pass is worse) ----------------

__global__ __launch_bounds__(256) void deg_part_kernel(
    const int* __restrict__ dst, int* __restrict__ deg, int E, int psize)
{
    const int part  = blockIdx.x % NPART;
    const int bslot = blockIdx.x / NPART;
    const int nb    = gridDim.x / NPART;
    const int lo = part * psize;
    const int hi = lo + psize;
    for (int e = bslot * 256 + threadIdx.x; e < E; e += nb * 256) {
        int d = dst[e];
        if (d >= lo && d < hi) atomicAdd(&deg[d], 1);
    }
}

// ---------------- CSR build ----------------

__global__ void scan_blocks(const int* __restrict__ deg, int* __restrict__ rp,
                            int* __restrict__ bsum, int N) {
    __shared__ int tmp[256];
    int t = threadIdx.x, i = blockIdx.x * 256 + t;
    int v = (i < N) ? deg[i] : 0;
    tmp[t] = v;
    __syncthreads();
    for (int off = 1; off < 256; off <<= 1) {
        int a = (t >= off) ? tmp[t - off] : 0;
        __syncthreads();
        tmp[t] += a;
        __syncthreads();
    }
    if (i < N) rp[i] = tmp[t] - v;
    if (t == 255) bsum[blockIdx.x] = tmp[255];
}

// folds bsum prefix (tree-reduce of bsum[0..blockIdx)) + dinv compute
__global__ void add_offsets_kernel(int* __restrict__ rp, const int* __restrict__ bsum,
                                   int* __restrict__ cursor, const int* __restrict__ deg,
                                   float* __restrict__ dinv, int N, int nb) {
    __shared__ int tmp[256];
    int t = threadIdx.x;
    tmp[t] = (t < nb && t < (int)blockIdx.x) ? bsum[t] : 0;
    __syncthreads();
    for (int s = 128; s > 0; s >>= 1) {
        if (t < s) tmp[t] += tmp[t + s];
        __syncthreads();
    }
    int base = tmp[0];
    int i = blockIdx.x * 256 + t;
    if (i < N) {
        int r = rp[i] + base;
        rp[i] = r;
        cursor[i] = r;
        dinv[i] = rsqrtf((float)(deg[i] + 1));   // +1 self-loop; always > 0
    }
}

// dst-partitioned CSR build (u16 payload).
__global__ __launch_bounds__(256) void build_csr_kernel(
    const int* __restrict__ src, const int* __restrict__ dst,
    int* __restrict__ cursor, unsigned short* __restrict__ csr_src,
    int E, int psize)
{
    const int part  = blockIdx.x % NPART;
    const int bslot = blockIdx.x / NPART;
    const int nb    = gridDim.x / NPART;
    const int lo = part * psize;
    const int hi = lo + psize;
    for (int e = bslot * 256 + threadIdx.x; e < E; e += nb * 256) {
        int d = dst[e];
        if (d >= lo && d < hi) {
            int pos = atomicAdd(&cursor[d], 1);
            csr_src[pos] = (unsigned short)src[e];
        }
    }
}

// ---------------- MFMA GEMM: g = fp16(dinv * (X @ W)) ----------------
// BM=64 (4 waves x 16 rows), BN=128 or 64. A from global (row-major X),
// B = Wt[n][k] fp16 staged in LDS with +8-half row pad.
// Fragment maps: A: m=lane&15, k=ks*32+(lane>>4)*8+j ; B: n=lane&15, same k.
// C/D: col=lane&15, row=(lane>>4)*4+reg  [HW-verified m89/m91].

template<int BN, typename XT>
__global__ __launch_bounds__(256) void gemm_mfma_kernel(
    const XT* __restrict__ X, const __half* __restrict__ Wt,
    const float* __restrict__ dinv, __half* __restrict__ g, int N)
{
    constexpr int K  = 128;
    constexpr int KP = K + 8;
    constexpr int NT = BN / 16;
    __shared__ __half Ws[BN * KP];

    const int tid = threadIdx.x;
    for (int c = tid; c < BN * (K / 8); c += 256) {
        int n  = c >> 4;
        int k8 = c & 15;
        *(f16x8*)&Ws[n * KP + k8 * 8] =
            *(const f16x8*)((const _Float16*)Wt + n * K + k8 * 8);
    }
    __syncthreads();

    const int lane = tid & 63;
    const int w    = tid >> 6;
    const int lrow = lane & 15;
    const int kg   = lane >> 4;
    const int row0 = blockIdx.x * 64 + w * 16;
    const int gr   = row0 + lrow;

    f32x4 acc[NT];
    #pragma unroll
    for (int t = 0; t < NT; ++t) acc[t] = (f32x4){0.f, 0.f, 0.f, 0.f};

    #pragma unroll
    for (int ks = 0; ks < 4; ++ks) {
        const int k0 = ks * 32 + kg * 8;
        f16x8 a = {};
        if constexpr (sizeof(XT) == 4) {
            if (gr < N) {
                const float* p = (const float*)X + (size_t)gr * K + k0;
                float4 x0 = *(const float4*)p;
                float4 x1 = *(const float4*)(p + 4);
                a[0] = (_Float16)x0.x; a[1] = (_Float16)x0.y;
                a[2] = (_Float16)x0.z; a[3] = (_Float16)x0.w;
                a[4] = (_Float16)x1.x; a[5] = (_Float16)x1.y;
                a[6] = (_Float16)x1.z; a[7] = (_Float16)x1.w;
            }
        } else {
            if (gr < N)
                a = *(const f16x8*)((const _Float16*)X + (size_t)gr * K + k0);
        }
        #pragma unroll
        for (int t = 0; t < NT; ++t) {
            f16x8 b = *(const f16x8*)&Ws[(t * 16 + lrow) * KP + k0];
            acc[t] = __builtin_amdgcn_mfma_f32_16x16x32_f16(a, b, acc[t], 0, 0, 0);
        }
    }

    #pragma unroll
    for (int r = 0; r < 4; ++r) {
        int m = row0 + kg * 4 + r;
        if (m < N) {
            float dn = dinv[m];
            #pragma unroll
            for (int t = 0; t < NT; ++t)
                g[(size_t)m * BN + t * 16 + lrow] = __float2half_rn(dn * acc[t][r]);
        }
    }
}

// ---------------- CSR aggregation + finalize ----------------
// 16 lanes per dst node (4 nodes/wave), 16B f16x8 gathers, 8-edge unroll.

template<int FO, bool RELU, typename OT>
__global__ __launch_bounds__(256) void aggregate_kernel(
    const __half* __restrict__ g, const int* __restrict__ rp, const int* __restrict__ deg,
    const unsigned short* __restrict__ csr, const float* __restrict__ dinv,
    const float* __restrict__ bias, OT* __restrict__ out, int N)
{
    constexpr int PER = FO / 16;   // 8 (FO=128) or 4 (FO=64)
    using VT = typename std::conditional<PER == 8, f16x8, f16x4>::type;

    int gid  = blockIdx.x * 256 + threadIdx.x;
    int node = gid >> 4;
    int lane = gid & 15;
    if (node >= N) return;

    int start = rp[node];
    int dg    = deg[node];

    const _Float16* gb = (const _Float16*)g + (size_t)lane * PER;

    float a[PER];
    {   // self-loop term
        VT v = *(const VT*)(gb + (size_t)node * FO);
        #pragma unroll
        for (int p = 0; p < PER; ++p) a[p] = (float)v[p];
    }

    int j = 0;
    for (; j + 7 < dg; j += 8) {
        int s[8];
        #pragma unroll
        for (int q = 0; q < 8; ++q) s[q] = csr[start + j + q];
        VT v[8];
        #pragma unroll
        for (int q = 0; q < 8; ++q) v[q] = *(const VT*)(gb + (size_t)s[q] * FO);
        #pragma unroll
        for (int p = 0; p < PER; ++p)
            a[p] += (((float)v[0][p] + (float)v[1][p]) + ((float)v[2][p] + (float)v[3][p]))
                  + (((float)v[4][p] + (float)v[5][p]) + ((float)v[6][p] + (float)v[7][p]));
    }
    for (; j + 3 < dg; j += 4) {
        int s0 = csr[start + j];
        int s1 = csr[start + j + 1];
        int s2 = csr[start + j + 2];
        int s3 = csr[start + j + 3];
        VT v0 = *(const VT*)(gb + (size_t)s0 * FO);
        VT v1 = *(const VT*)(gb + (size_t)s1 * FO);
        VT v2 = *(const VT*)(gb + (size_t)s2 * FO);
        VT v3 = *(const VT*)(gb + (size_t)s3 * FO);
        #pragma unroll
        for (int p = 0; p < PER; ++p)
            a[p] += ((float)v0[p] + (float)v1[p]) + ((float)v2[p] + (float)v3[p]);
    }
    for (; j < dg; ++j) {
        int s0 = csr[start + j];
        VT v0 = *(const VT*)(gb + (size_t)s0 * FO);
        #pragma unroll
        for (int p = 0; p < PER; ++p) a[p] += (float)v0[p];
    }

    float dn = dinv[node];
    float o[PER];
    #pragma unroll
    for (int p = 0; p < PER; ++p) {
        o[p] = fmaf(dn, a[p], bias[lane * PER + p]);
        if (RELU) o[p] = fmaxf(o[p], 0.f);
    }

    if constexpr (sizeof(OT) == 2) {
        VT h;
        #pragma unroll
        for (int p = 0; p < PER; ++p) h[p] = (_Float16)o[p];
        *(VT*)((_Float16*)out + (size_t)node * FO + lane * PER) = h;
    } else {
        float* op = (float*)out + (size_t)node * FO + lane * PER;
        #pragma unroll
        for (int q = 0; q < PER / 4; ++q)
            *(float4*)(op + 4 * q) = make_float4(o[4 * q], o[4 * q + 1],
                                                 o[4 * q + 2], o[4 * q + 3]);
    }
}

// ---------------- launch ----------------

extern "C" void kernel_launch(void* const* d_in, const int* in_sizes, int n_in,
                              void* d_out, int out_size, void* d_ws, size_t ws_size,
                              hipStream_t stream) {
    const float* x  = (const float*)d_in[0];
    const int*   ei = (const int*)d_in[1];    // harness passes integer inputs as int32
    const float* W0 = (const float*)d_in[2];
    const float* b0 = (const float*)d_in[3];
    const float* W1 = (const float*)d_in[4];
    const float* b1 = (const float*)d_in[5];
    const float* W2 = (const float*)d_in[6];
    const float* b2 = (const float*)d_in[7];
    float* out = (float*)d_out;

    const int N = in_sizes[0] / F_IN;
    const int E = in_sizes[1] / 2;
    const int* src = ei;
    const int* dst = ei + E;

    char* ws = (char*)d_ws;
    size_t off = 0;
    __half* bufA  = (__half*)(ws + off); off += (size_t)N * 128 * 2;  // g (fp16)
    __half* bufB  = (__half*)(ws + off); off += (size_t)N * 128 * 2;  // features (fp16)
    float* dinv   = (float*)(ws + off); off += (size_t)N * 4;
    int*   deg    = (int*)  (ws + off); off += (size_t)N * 4;
    int*   rowptr = (int*)  (ws + off); off += (size_t)N * 4;
    int*   cursor = (int*)  (ws + off); off += (size_t)N * 4;
    int*   bsum   = (int*)  (ws + off); off += 256 * 4;
    unsigned short* csr = (unsigned short*)(ws + off); off += (size_t)E * 2;
    off = (off + 255) & ~(size_t)255;
    __half* wt0 = (__half*)(ws + off); off += 128 * 128 * 2;
    __half* wt1 = (__half*)(ws + off); off += 128 * 128 * 2;
    __half* wt2 = (__half*)(ws + off); off += 64 * 128 * 2;

    const int nb_nodes = (N + 255) / 256;   // 196 blocks -> fits 256-wide bsum reduce
    const int nb_setup = (((N > 40960 ? N : 40960) + 255) / 256);
    const int nb_aggr  = (N * 16 + 255) / 256;
    const int nb_gemm  = (N + 63) / 64;
    const int psize    = (N + NPART - 1) / NPART;

    setup_kernel<<<nb_setup, 256, 0, stream>>>(W0, W1, W2, wt0, wt1, wt2, deg, N);
    deg_part_kernel<<<NPART * 128, 256, 0, stream>>>(dst, deg, E, psize);
    scan_blocks<<<nb_nodes, 256, 0, stream>>>(deg, rowptr, bsum, N);
    add_offsets_kernel<<<nb_nodes, 256, 0, stream>>>(rowptr, bsum, cursor, deg, dinv, N, nb_nodes);
    build_csr_kernel<<<NPART * 128, 256, 0, stream>>>(src, dst, cursor, csr, E, psize);

    // ---- layer 0: x (fp32) -> bufA (g fp16) -> bufB (fp16) ----
    gemm_mfma_kernel<128, float><<<nb_gemm, 256, 0, stream>>>(x, wt0, dinv, bufA, N);
    aggregate_kernel<128, true, __half><<<nb_aggr, 256, 0, stream>>>(bufA, rowptr, deg, csr, dinv, b0, bufB, N);

    // ---- layer 1: bufB (fp16) -> bufA (g fp16) -> bufB (fp16) ----
    gemm_mfma_kernel<128, __half><<<nb_gemm, 256, 0, stream>>>(bufB, wt1, dinv, bufA, N);
    aggregate_kernel<128, true, __half><<<nb_aggr, 256, 0, stream>>>(bufA, rowptr, deg, csr, dinv, b1, bufB, N);

    // ---- layer 2: bufB (fp16) -> bufA (g fp16, N*64) -> out (fp32) ----
    gemm_mfma_kernel<64, __half><<<nb_gemm, 256, 0, stream>>>(bufB, wt2, dinv, bufA, N);
    aggregate_kernel<64, false, float><<<nb_aggr, 256, 0, stream>>>(bufA, rowptr, deg, csr, dinv, b2, out, N);
}